// Round 3
// baseline (187.061 us; speedup 1.0000x reference)
//
#include <hip/hip_runtime.h>
#include <hip/hip_bf16.h>
#include <stdint.h>

#define BB   8
#define CIN  256
#define CI   128
#define NN   4096
#define EPSV 1e-5f
#define LOG2E 1.44269504088896340736f

typedef __attribute__((ext_vector_type(8))) short bf16x8;
typedef __attribute__((ext_vector_type(4))) short bf16x4;
typedef __attribute__((ext_vector_type(4))) float f32x4;
typedef __attribute__((ext_vector_type(2))) unsigned int u32x2;

static __device__ inline short f2bf(float f) {
    uint32_t u = __builtin_bit_cast(uint32_t, f);
    u += 0x7FFFu + ((u >> 16) & 1u);   // round-to-nearest-even
    return (short)(u >> 16);
}

static __device__ inline uint32_t cvt_pk_bf16(float lo, float hi) {
    uint32_t r;
    asm("v_cvt_pk_bf16_f32 %0, %1, %2" : "=v"(r) : "v"(lo), "v"(hi));
    return r;
}

// ---------------------------------------------------------------------------
// Kernel 1: BN + the three 1x1 projections (theta->Q, phi->K, g->V^T), bf16 out
// Q (theta) is pre-scaled by log2(e) so attn can use raw v_exp_f32 (exp2).
// ---------------------------------------------------------------------------
__global__ __launch_bounds__(256) void proj_kernel(
    const float* __restrict__ x,
    const float* __restrict__ gamma, const float* __restrict__ beta,
    const float* __restrict__ mean,  const float* __restrict__ var,
    const float* __restrict__ wg,  const float* __restrict__ bg,
    const float* __restrict__ wth, const float* __restrict__ bth,
    const float* __restrict__ wph, const float* __restrict__ bph,
    short* __restrict__ qp, short* __restrict__ kp, short* __restrict__ vtp)
{
    __shared__ float s_scale[CIN];
    __shared__ float s_shift[CIN];
    __shared__ __align__(16) short A_lds[64][72];    // [n][c], pad 72 -> 2-way free
    __shared__ __align__(16) short B_lds[128][72];   // [o][c]

    const int tid = threadIdx.x;
    const int bid = blockIdx.x;
    const int s   = bid / (BB * 64);          // 0=theta,1=phi,2=g
    const int r   = bid % (BB * 64);
    const int b   = r / 64;
    const int n0  = (r % 64) * 64;

    {   // BN scale/shift (256 threads == 256 channels)
        float sc = gamma[tid] * rsqrtf(var[tid] + EPSV);
        s_scale[tid] = sc;
        s_shift[tid] = beta[tid] - mean[tid] * sc;
    }
    __syncthreads();

    const float* wsrc = (s == 0) ? wth : (s == 1) ? wph : wg;
    const float* bsrc = (s == 0) ? bth : (s == 1) ? bph : bg;

    const int w = tid >> 6, lane = tid & 63, lr = lane & 15, lg = lane >> 4;

    f32x4 acc[8];
    #pragma unroll
    for (int i = 0; i < 8; ++i) acc[i] = (f32x4){0.f, 0.f, 0.f, 0.f};

    for (int c0 = 0; c0 < CIN; c0 += 64) {
        // stage A: BN(x) transposed to [n][c]
        #pragma unroll
        for (int pass = 0; pass < 4; ++pass) {
            int c  = c0 + pass * 16 + (tid >> 4);
            int n4 = (tid & 15) * 4;
            f32x4 v = *(const f32x4*)&x[((size_t)b * CIN + c) * NN + n0 + n4];
            float sc = s_scale[c], sh = s_shift[c];
            #pragma unroll
            for (int i = 0; i < 4; ++i)
                A_lds[n4 + i][c - c0] = f2bf(v[i] * sc + sh);
        }
        // stage B: weights [o][c]
        #pragma unroll
        for (int pass = 0; pass < 8; ++pass) {
            int o  = pass * 16 + (tid >> 4);
            int c4 = (tid & 15) * 4;
            f32x4 v = *(const f32x4*)&wsrc[(size_t)o * CIN + c0 + c4];
            bf16x4 bv;
            #pragma unroll
            for (int i = 0; i < 4; ++i) bv[i] = f2bf(v[i]);
            *(bf16x4*)&B_lds[o][c4] = bv;
        }
        __syncthreads();

        bf16x8 a0 = *(const bf16x8*)&A_lds[w * 16 + lr][lg * 8];
        bf16x8 a1 = *(const bf16x8*)&A_lds[w * 16 + lr][32 + lg * 8];
        #pragma unroll
        for (int ot = 0; ot < 8; ++ot) {
            bf16x8 b0 = *(const bf16x8*)&B_lds[ot * 16 + lr][lg * 8];
            bf16x8 b1 = *(const bf16x8*)&B_lds[ot * 16 + lr][32 + lg * 8];
            acc[ot] = __builtin_amdgcn_mfma_f32_16x16x32_bf16(a0, b0, acc[ot], 0, 0, 0);
            acc[ot] = __builtin_amdgcn_mfma_f32_16x16x32_bf16(a1, b1, acc[ot], 0, 0, 0);
        }
        __syncthreads();
    }

    if (s < 2) {   // Q / K: (b, n, c) row-major; Q scaled by log2e
        short* dst = (s == 0) ? qp : kp;
        const float om = (s == 0) ? LOG2E : 1.0f;
        #pragma unroll
        for (int ot = 0; ot < 8; ++ot) {
            float bias = bsrc[ot * 16 + lr];
            #pragma unroll
            for (int rr = 0; rr < 4; ++rr) {
                int n = n0 + w * 16 + lg * 4 + rr;
                dst[((size_t)b * NN + n) * CI + ot * 16 + lr] = f2bf((acc[ot][rr] + bias) * om);
            }
        }
    } else {       // V^T: (b, c, n)
        #pragma unroll
        for (int ot = 0; ot < 8; ++ot) {
            float bias = bsrc[ot * 16 + lr];
            bf16x4 pk;
            #pragma unroll
            for (int rr = 0; rr < 4; ++rr) pk[rr] = f2bf(acc[ot][rr] + bias);
            *(bf16x4*)&vtp[((size_t)b * CI + ot * 16 + lr) * NN + n0 + w * 16 + lg * 4] = pk;
        }
    }
}

// ---------------------------------------------------------------------------
// Kernel 2: flash attention. 4 waves x 2 Q-strips (128 q-rows/block), KVBLK=64,
// grid 256 = 8 batch x 32 tiles, batch = blockIdx&7 (XCD-pinned -> L2-resident
// K/V). Swapped QK^T, in-register softmax w/ defer-max, cvt_pk P-packing,
// XOR-swizzled K/V/P. Double-buffered K/V via global_load_lds.
// ---------------------------------------------------------------------------
__global__ __launch_bounds__(256) void attn_kernel(
    const short* __restrict__ qp, const short* __restrict__ kp,
    const short* __restrict__ vtp, short* __restrict__ yp)
{
    __shared__ __align__(16) char K_sh[2][64 * 256];    // [m][c] swizzled, 16KB x2
    __shared__ __align__(16) char V_sh[2][128 * 128];   // [c][m] swizzled, 16KB x2
    __shared__ __align__(16) char P_sh[8][16 * 128];    // [w*2+s][q][m] swizzled

    const int tid = threadIdx.x;
    const int b   = blockIdx.x & 7;            // batch == XCD (round-robin dispatch)
    const int n0  = (blockIdx.x >> 3) * 128;
    const int w = tid >> 6, lane = tid & 63, lr = lane & 15, lg = lane >> 4;

    const short* kbatch = kp  + (size_t)b * NN * CI;
    const short* vbatch = vtp + (size_t)b * CI * NN;

    // stage K/V tile t into buffer bufi: linear LDS dest, inverse-swizzled source
    auto stage = [&](int bufi, int t) {
        const short* ksrc = kbatch + (size_t)t * 64 * CI;
        const short* vsrc = vbatch + (size_t)t * 64;
        #pragma unroll
        for (int r = 0; r < 4; ++r) {
            int idx = ((r * 4 + w) << 6) + lane;          // 16B-chunk index 0..1023
            int mm  = idx >> 4, cb = (idx & 15) << 4;     // K: row m, dest col-byte
            const char* gk = (const char*)(ksrc + (size_t)mm * CI) + (cb ^ ((mm & 7) << 4));
            __builtin_amdgcn_global_load_lds(
                (const __attribute__((address_space(1))) void*)gk,
                (__attribute__((address_space(3))) void*)&K_sh[bufi][(r * 4 + w) << 10],
                16, 0, 0);
            int cc = idx >> 3, cbv = (idx & 7) << 4;      // V: row c, dest col-byte
            const char* gv = (const char*)(vsrc + (size_t)cc * NN) + (cbv ^ ((cc & 7) << 4));
            __builtin_amdgcn_global_load_lds(
                (const __attribute__((address_space(1))) void*)gv,
                (__attribute__((address_space(3))) void*)&V_sh[bufi][(r * 4 + w) << 10],
                16, 0, 0);
        }
    };

    // Q strips in registers (B-frag for mfma(K,Q): col=q=lr, k contiguous)
    bf16x8 qf[2][4];
    #pragma unroll
    for (int s = 0; s < 2; ++s) {
        const short* qrow = qp + ((size_t)b * NN + n0 + w * 32 + s * 16 + lr) * CI;
        #pragma unroll
        for (int kf = 0; kf < 4; ++kf)
            qf[s][kf] = *(const bf16x8*)&qrow[kf * 32 + lg * 8];
    }

    f32x4 yacc[2][8];
    #pragma unroll
    for (int s = 0; s < 2; ++s)
        #pragma unroll
        for (int i = 0; i < 8; ++i) yacc[s][i] = (f32x4){0.f, 0.f, 0.f, 0.f};
    float m_run[2] = {-__builtin_huge_valf(), -__builtin_huge_valf()};
    float l_run[2] = {0.f, 0.f};

    stage(0, 0);
    __syncthreads();

    for (int t = 0; t < NN / 64; ++t) {
        const int cur = t & 1;
        if (t + 1 < NN / 64) stage(cur ^ 1, t + 1);   // issue before compute

        // S^T = K Q : lane (lr,lg) holds S[q=lr][m=mt*16+lg*4+rr] per strip
        const char* Kc = K_sh[cur];
        f32x4 sa[2][4];
        __builtin_amdgcn_s_setprio(1);
        #pragma unroll
        for (int mt = 0; mt < 4; ++mt) {
            const int mrow = mt * 16 + lr;
            const int sw   = (mrow & 7) << 4;
            sa[0][mt] = (f32x4){0.f, 0.f, 0.f, 0.f};
            sa[1][mt] = (f32x4){0.f, 0.f, 0.f, 0.f};
            #pragma unroll
            for (int kf = 0; kf < 4; ++kf) {
                bf16x8 kfrag = *(const bf16x8*)(Kc + (mrow << 8) + ((kf * 64 + lg * 16) ^ sw));
                sa[0][mt] = __builtin_amdgcn_mfma_f32_16x16x32_bf16(kfrag, qf[0][kf], sa[0][mt], 0, 0, 0);
                sa[1][mt] = __builtin_amdgcn_mfma_f32_16x16x32_bf16(kfrag, qf[1][kf], sa[1][mt], 0, 0, 0);
            }
        }
        __builtin_amdgcn_s_setprio(0);

        // per-strip row-max (q = lr; m spread over regs and lg)
        float tmv[2];
        #pragma unroll
        for (int s = 0; s < 2; ++s) {
            float tm = fmaxf(fmaxf(fmaxf(sa[s][0][0], sa[s][0][1]), fmaxf(sa[s][0][2], sa[s][0][3])),
                             fmaxf(fmaxf(sa[s][1][0], sa[s][1][1]), fmaxf(sa[s][1][2], sa[s][1][3])));
            tm = fmaxf(tm, fmaxf(fmaxf(fmaxf(sa[s][2][0], sa[s][2][1]), fmaxf(sa[s][2][2], sa[s][2][3])),
                                 fmaxf(fmaxf(sa[s][3][0], sa[s][3][1]), fmaxf(sa[s][3][2], sa[s][3][3]))));
            tm = fmaxf(tm, __shfl_xor(tm, 16));
            tm = fmaxf(tm, __shfl_xor(tm, 32));
            tmv[s] = tm;
        }

        // defer-max (T13): rescale only when max grows > 8 (log2 units)
        int need = (tmv[0] - m_run[0] > 8.f) || (tmv[1] - m_run[1] > 8.f);
        if (__any(need)) {
            #pragma unroll
            for (int s = 0; s < 2; ++s) {
                float mnew = fmaxf(m_run[s], tmv[s]);
                float sc   = __builtin_amdgcn_exp2f(m_run[s] - mnew);
                m_run[s] = mnew;
                l_run[s] *= sc;
                #pragma unroll
                for (int rr = 0; rr < 4; ++rr) {
                    float scb = __shfl(sc, (lane & 48) | (lg * 4 + rr));
                    #pragma unroll
                    for (int ct = 0; ct < 8; ++ct) yacc[s][ct][rr] *= scb;
                }
            }
        }

        // P = exp2(S - m), packed via v_cvt_pk_bf16_f32, swizzled LDS write
        #pragma unroll
        for (int s = 0; s < 2; ++s) {
            char* Pb = P_sh[(w << 1) + s];
            float rs = 0.f;
            #pragma unroll
            for (int mt = 0; mt < 4; ++mt) {
                float e0 = __builtin_amdgcn_exp2f(sa[s][mt][0] - m_run[s]);
                float e1 = __builtin_amdgcn_exp2f(sa[s][mt][1] - m_run[s]);
                float e2 = __builtin_amdgcn_exp2f(sa[s][mt][2] - m_run[s]);
                float e3 = __builtin_amdgcn_exp2f(sa[s][mt][3] - m_run[s]);
                rs += (e0 + e1) + (e2 + e3);
                u32x2 pk = {cvt_pk_bf16(e0, e1), cvt_pk_bf16(e2, e3)};
                *(u32x2*)(Pb + lr * 128 + ((mt * 32 + lg * 8) ^ ((lr & 7) << 4))) = pk;
            }
            rs += __shfl_xor(rs, 16);
            rs += __shfl_xor(rs, 32);
            l_run[s] += rs;
        }

        asm volatile("" ::: "memory");   // order P write -> read (same wave)

        // Y += P V  (V-frags shared across strips)
        const char* Vc = V_sh[cur];
        __builtin_amdgcn_s_setprio(1);
        #pragma unroll
        for (int kf = 0; kf < 2; ++kf) {
            const int psw = (kf * 64 + lg * 16) ^ ((lr & 7) << 4);
            bf16x8 pa0 = *(const bf16x8*)(P_sh[(w << 1) + 0] + lr * 128 + psw);
            bf16x8 pa1 = *(const bf16x8*)(P_sh[(w << 1) + 1] + lr * 128 + psw);
            #pragma unroll
            for (int ct = 0; ct < 8; ++ct) {
                const int vr = ct * 16 + lr;
                bf16x8 vf = *(const bf16x8*)(Vc + (vr << 7) +
                                             ((kf * 64 + lg * 16) ^ ((vr & 7) << 4)));
                yacc[0][ct] = __builtin_amdgcn_mfma_f32_16x16x32_bf16(pa0, vf, yacc[0][ct], 0, 0, 0);
                yacc[1][ct] = __builtin_amdgcn_mfma_f32_16x16x32_bf16(pa1, vf, yacc[1][ct], 0, 0, 0);
            }
        }
        __builtin_amdgcn_s_setprio(0);

        __syncthreads();   // drains vmcnt: next tile staged; buf[cur] reads done
    }

    // normalize + store Y^T (b, n, c): yacc[s][ct][rr] = Y[q=lg*4+rr][c=ct*16+lr]
    #pragma unroll
    for (int s = 0; s < 2; ++s) {
        #pragma unroll
        for (int rr = 0; rr < 4; ++rr) {
            float li  = __shfl(l_run[s], (lane & 48) | (lg * 4 + rr));
            float inv = 1.0f / li;
            int n = n0 + w * 32 + s * 16 + lg * 4 + rr;
            #pragma unroll
            for (int ct = 0; ct < 8; ++ct)
                yp[((size_t)b * NN + n) * CI + ct * 16 + lr] = f2bf(yacc[s][ct][rr] * inv);
        }
    }
}

// ---------------------------------------------------------------------------
// Kernel 3: out = w_w @ Y + b_w + x.  M=o (coalesced n-stores), 128x128 tiles.
// ---------------------------------------------------------------------------
__global__ __launch_bounds__(256) void out_kernel(
    const short* __restrict__ yp, const float* __restrict__ ww,
    const float* __restrict__ bw, const float* __restrict__ x,
    float* __restrict__ out)
{
    __shared__ __align__(16) short A_lds[128][136];   // w_w [o][c]
    __shared__ __align__(16) short Bl[128][136];      // Y^T [n][c]

    const int tid = threadIdx.x;
    const int ob = blockIdx.x & 1;
    const int g  = blockIdx.x >> 1;
    const int b  = g >> 5;
    const int nn = (g & 31) * 128;
    const int o0 = ob * 128;
    const int w = tid >> 6, lane = tid & 63, lr = lane & 15, lg = lane >> 4;

    #pragma unroll
    for (int pass = 0; pass < 8; ++pass) {
        int o  = pass * 16 + (tid >> 4);
        int c8 = (tid & 15) * 8;
        f32x4 v0 = *(const f32x4*)&ww[(size_t)(o0 + o) * CI + c8];
        f32x4 v1 = *(const f32x4*)&ww[(size_t)(o0 + o) * CI + c8 + 4];
        bf16x8 bv;
        #pragma unroll
        for (int i = 0; i < 4; ++i) { bv[i] = f2bf(v0[i]); bv[4 + i] = f2bf(v1[i]); }
        *(bf16x8*)&A_lds[o][c8] = bv;
    }
    #pragma unroll
    for (int pass = 0; pass < 8; ++pass) {
        int n  = pass * 16 + (tid >> 4);
        int c8 = (tid & 15) * 8;
        *(bf16x8*)&Bl[n][c8] = *(const bf16x8*)&yp[((size_t)b * NN + nn + n) * CI + c8];
    }
    __syncthreads();

    f32x4 acc[2][8];
    #pragma unroll
    for (int i = 0; i < 2; ++i)
        #pragma unroll
        for (int j = 0; j < 8; ++j) acc[i][j] = (f32x4){0.f, 0.f, 0.f, 0.f};

    #pragma unroll
    for (int kf = 0; kf < 4; ++kf) {
        bf16x8 a0 = *(const bf16x8*)&A_lds[w * 32 + lr][kf * 32 + lg * 8];
        bf16x8 a1 = *(const bf16x8*)&A_lds[w * 32 + 16 + lr][kf * 32 + lg * 8];
        #pragma unroll
        for (int nt = 0; nt < 8; ++nt) {
            bf16x8 bv = *(const bf16x8*)&Bl[nt * 16 + lr][kf * 32 + lg * 8];
            acc[0][nt] = __builtin_amdgcn_mfma_f32_16x16x32_bf16(a0, bv, acc[0][nt], 0, 0, 0);
            acc[1][nt] = __builtin_amdgcn_mfma_f32_16x16x32_bf16(a1, bv, acc[1][nt], 0, 0, 0);
        }
    }

    #pragma unroll
    for (int wo = 0; wo < 2; ++wo) {
        #pragma unroll
        for (int rr = 0; rr < 4; ++rr) {
            int o = o0 + w * 32 + wo * 16 + lg * 4 + rr;
            float bias = bw[o];
            #pragma unroll
            for (int nt = 0; nt < 8; ++nt) {
                size_t idx = ((size_t)b * CIN + o) * NN + nn + nt * 16 + lr;
                out[idx] = acc[wo][nt][rr] + bias + x[idx];
            }
        }
    }
}

// ---------------------------------------------------------------------------
extern "C" void kernel_launch(void* const* d_in, const int* in_sizes, int n_in,
                              void* d_out, int out_size, void* d_ws, size_t ws_size,
                              hipStream_t stream)
{
    const float* x     = (const float*)d_in[0];
    const float* gamma = (const float*)d_in[1];
    const float* beta  = (const float*)d_in[2];
    const float* mean  = (const float*)d_in[3];
    const float* var   = (const float*)d_in[4];
    const float* wg    = (const float*)d_in[5];
    const float* bg    = (const float*)d_in[6];
    const float* wth   = (const float*)d_in[7];
    const float* bth   = (const float*)d_in[8];
    const float* wph   = (const float*)d_in[9];
    const float* bph   = (const float*)d_in[10];
    const float* ww    = (const float*)d_in[11];
    const float* bw    = (const float*)d_in[12];

    const size_t seg = (size_t)BB * NN * CI;
    short* qp  = (short*)d_ws;
    short* kp  = qp + seg;
    short* vtp = kp + seg;
    short* yp  = vtp + seg;
    (void)in_sizes; (void)n_in; (void)out_size; (void)ws_size;

    proj_kernel<<<3 * BB * (NN / 64), 256, 0, stream>>>(
        x, gamma, beta, mean, var, wg, bg, wth, bth, wph, bph, qp, kp, vtp);
    attn_kernel<<<2 * BB * (NN / 256), 256, 0, stream>>>(qp, kp, vtp, yp);
    out_kernel<<<2 * BB * (NN / 128), 256, 0, stream>>>(yp, ww, bw, x, (float*)d_out);
}

// Round 4
// 152.231 us; speedup vs baseline: 1.2288x; 1.2288x over previous
//
#include <hip/hip_runtime.h>
#include <hip/hip_bf16.h>
#include <stdint.h>

#define BB   8
#define CIN  256
#define CI   128
#define NN   4096
#define EPSV 1e-5f
#define LOG2E 1.44269504088896340736f

typedef __attribute__((ext_vector_type(8))) short bf16x8;
typedef __attribute__((ext_vector_type(4))) short bf16x4;
typedef __attribute__((ext_vector_type(4))) float f32x4;
typedef __attribute__((ext_vector_type(2))) float f32x2;
typedef __attribute__((ext_vector_type(2))) unsigned int u32x2;

static __device__ inline short f2bf(float f) {
    uint32_t u = __builtin_bit_cast(uint32_t, f);
    u += 0x7FFFu + ((u >> 16) & 1u);   // round-to-nearest-even
    return (short)(u >> 16);
}

static __device__ inline uint32_t cvt_pk_bf16(float lo, float hi) {
    uint32_t r;
    asm("v_cvt_pk_bf16_f32 %0, %1, %2" : "=v"(r) : "v"(lo), "v"(hi));
    return r;
}

// ---------------------------------------------------------------------------
// Kernel 1: BN + the three 1x1 projections (theta->Q, phi->K, g->V^T), bf16 out
// Q (theta) is pre-scaled by log2(e) so attn can use raw v_exp_f32 (exp2).
// ---------------------------------------------------------------------------
__global__ __launch_bounds__(256) void proj_kernel(
    const float* __restrict__ x,
    const float* __restrict__ gamma, const float* __restrict__ beta,
    const float* __restrict__ mean,  const float* __restrict__ var,
    const float* __restrict__ wg,  const float* __restrict__ bg,
    const float* __restrict__ wth, const float* __restrict__ bth,
    const float* __restrict__ wph, const float* __restrict__ bph,
    short* __restrict__ qp, short* __restrict__ kp, short* __restrict__ vtp)
{
    __shared__ float s_scale[CIN];
    __shared__ float s_shift[CIN];
    __shared__ __align__(16) short A_lds[64][72];    // [n][c], pad 72 -> 2-way free
    __shared__ __align__(16) short B_lds[128][72];   // [o][c]

    const int tid = threadIdx.x;
    const int bid = blockIdx.x;
    const int s   = bid / (BB * 64);          // 0=theta,1=phi,2=g
    const int r   = bid % (BB * 64);
    const int b   = r / 64;
    const int n0  = (r % 64) * 64;

    {   // BN scale/shift (256 threads == 256 channels)
        float sc = gamma[tid] * rsqrtf(var[tid] + EPSV);
        s_scale[tid] = sc;
        s_shift[tid] = beta[tid] - mean[tid] * sc;
    }
    __syncthreads();

    const float* wsrc = (s == 0) ? wth : (s == 1) ? wph : wg;
    const float* bsrc = (s == 0) ? bth : (s == 1) ? bph : bg;

    const int w = tid >> 6, lane = tid & 63, lr = lane & 15, lg = lane >> 4;

    f32x4 acc[8];
    #pragma unroll
    for (int i = 0; i < 8; ++i) acc[i] = (f32x4){0.f, 0.f, 0.f, 0.f};

    for (int c0 = 0; c0 < CIN; c0 += 64) {
        // stage A: BN(x) transposed to [n][c]
        #pragma unroll
        for (int pass = 0; pass < 4; ++pass) {
            int c  = c0 + pass * 16 + (tid >> 4);
            int n4 = (tid & 15) * 4;
            f32x4 v = *(const f32x4*)&x[((size_t)b * CIN + c) * NN + n0 + n4];
            float sc = s_scale[c], sh = s_shift[c];
            #pragma unroll
            for (int i = 0; i < 4; ++i)
                A_lds[n4 + i][c - c0] = f2bf(v[i] * sc + sh);
        }
        // stage B: weights [o][c]
        #pragma unroll
        for (int pass = 0; pass < 8; ++pass) {
            int o  = pass * 16 + (tid >> 4);
            int c4 = (tid & 15) * 4;
            f32x4 v = *(const f32x4*)&wsrc[(size_t)o * CIN + c0 + c4];
            bf16x4 bv;
            #pragma unroll
            for (int i = 0; i < 4; ++i) bv[i] = f2bf(v[i]);
            *(bf16x4*)&B_lds[o][c4] = bv;
        }
        __syncthreads();

        bf16x8 a0 = *(const bf16x8*)&A_lds[w * 16 + lr][lg * 8];
        bf16x8 a1 = *(const bf16x8*)&A_lds[w * 16 + lr][32 + lg * 8];
        #pragma unroll
        for (int ot = 0; ot < 8; ++ot) {
            bf16x8 b0 = *(const bf16x8*)&B_lds[ot * 16 + lr][lg * 8];
            bf16x8 b1 = *(const bf16x8*)&B_lds[ot * 16 + lr][32 + lg * 8];
            acc[ot] = __builtin_amdgcn_mfma_f32_16x16x32_bf16(a0, b0, acc[ot], 0, 0, 0);
            acc[ot] = __builtin_amdgcn_mfma_f32_16x16x32_bf16(a1, b1, acc[ot], 0, 0, 0);
        }
        __syncthreads();
    }

    if (s < 2) {   // Q / K: (b, n, c) row-major; Q scaled by log2e
        short* dst = (s == 0) ? qp : kp;
        const float om = (s == 0) ? LOG2E : 1.0f;
        #pragma unroll
        for (int ot = 0; ot < 8; ++ot) {
            float bias = bsrc[ot * 16 + lr];
            #pragma unroll
            for (int rr = 0; rr < 4; ++rr) {
                int n = n0 + w * 16 + lg * 4 + rr;
                dst[((size_t)b * NN + n) * CI + ot * 16 + lr] = f2bf((acc[ot][rr] + bias) * om);
            }
        }
    } else {       // V^T: (b, c, n)
        #pragma unroll
        for (int ot = 0; ot < 8; ++ot) {
            float bias = bsrc[ot * 16 + lr];
            bf16x4 pk;
            #pragma unroll
            for (int rr = 0; rr < 4; ++rr) pk[rr] = f2bf(acc[ot][rr] + bias);
            *(bf16x4*)&vtp[((size_t)b * CI + ot * 16 + lr) * NN + n0 + w * 16 + lg * 4] = pk;
        }
    }
}

// ---------------------------------------------------------------------------
// Kernel 2: flash attention, SPLIT-KV. grid 512 = 8 batch x 2 kv-half x 32
// q-tiles -> 2 blocks/CU (2 waves/SIMD, latency hiding). 4 waves x 2 Q-strips.
// LDS 72KB (K 32 + V 32 + P 8) so two blocks co-reside. Writes UNNORMALIZED
// partial Yhat (fp32, into d_out used as scratch) + per-row (m,l) to ml.
// ---------------------------------------------------------------------------
__global__ __launch_bounds__(256, 2) void attn_kernel(
    const short* __restrict__ qp, const short* __restrict__ kp,
    const short* __restrict__ vtp, float* __restrict__ yh,
    float* __restrict__ ml)
{
    __shared__ __align__(16) char K_sh[2][64 * 256];    // [m][c] swizzled, 16KB x2
    __shared__ __align__(16) char V_sh[2][128 * 128];   // [c][m] swizzled, 16KB x2
    __shared__ __align__(16) char P_sh[4][16 * 128];    // per-wave single P buf

    const int tid  = threadIdx.x;
    const int b    = blockIdx.x & 7;            // batch == XCD (round-robin)
    const int half = (blockIdx.x >> 3) & 1;     // kv half
    const int n0   = (blockIdx.x >> 4) * 128;
    const int w = tid >> 6, lane = tid & 63, lr = lane & 15, lg = lane >> 4;
    const int NT = NN / 128;                    // 32 kv tiles per half

    const short* kbatch = kp  + (size_t)b * NN * CI;
    const short* vbatch = vtp + (size_t)b * CI * NN;
    const int t0 = half * NT;                   // global tile offset

    // stage K/V tile (t0+t) into buffer bufi: linear LDS dest, pre-swizzled src
    auto stage = [&](int bufi, int t) {
        const short* ksrc = kbatch + (size_t)(t0 + t) * 64 * CI;
        const short* vsrc = vbatch + (size_t)(t0 + t) * 64;
        #pragma unroll
        for (int r = 0; r < 4; ++r) {
            int idx = ((r * 4 + w) << 6) + lane;          // 16B-chunk index 0..1023
            int mm  = idx >> 4, cb = (idx & 15) << 4;     // K: row m, dest col-byte
            const char* gk = (const char*)(ksrc + (size_t)mm * CI) + (cb ^ ((mm & 7) << 4));
            __builtin_amdgcn_global_load_lds(
                (const __attribute__((address_space(1))) void*)gk,
                (__attribute__((address_space(3))) void*)&K_sh[bufi][(r * 4 + w) << 10],
                16, 0, 0);
            int cc = idx >> 3, cbv = (idx & 7) << 4;      // V: row c, dest col-byte
            const char* gv = (const char*)(vsrc + (size_t)cc * NN) + (cbv ^ ((cc & 7) << 4));
            __builtin_amdgcn_global_load_lds(
                (const __attribute__((address_space(1))) void*)gv,
                (__attribute__((address_space(3))) void*)&V_sh[bufi][(r * 4 + w) << 10],
                16, 0, 0);
        }
    };

    // Q strips in registers (B-frag for mfma(K,Q): col=q=lr, k contiguous)
    bf16x8 qf[2][4];
    #pragma unroll
    for (int s = 0; s < 2; ++s) {
        const short* qrow = qp + ((size_t)b * NN + n0 + w * 32 + s * 16 + lr) * CI;
        #pragma unroll
        for (int kf = 0; kf < 4; ++kf)
            qf[s][kf] = *(const bf16x8*)&qrow[kf * 32 + lg * 8];
    }

    f32x4 yacc[2][8];
    #pragma unroll
    for (int s = 0; s < 2; ++s)
        #pragma unroll
        for (int i = 0; i < 8; ++i) yacc[s][i] = (f32x4){0.f, 0.f, 0.f, 0.f};
    float m_run[2] = {-__builtin_huge_valf(), -__builtin_huge_valf()};
    float l_run[2] = {0.f, 0.f};

    stage(0, 0);
    __syncthreads();

    for (int t = 0; t < NT; ++t) {
        const int cur = t & 1;
        if (t + 1 < NT) stage(cur ^ 1, t + 1);   // issue before compute

        // S^T = K Q : lane (lr,lg) holds S[q=lr][m=mt*16+lg*4+rr] per strip
        const char* Kc = K_sh[cur];
        f32x4 sa[2][4];
        __builtin_amdgcn_s_setprio(1);
        #pragma unroll
        for (int mt = 0; mt < 4; ++mt) {
            const int mrow = mt * 16 + lr;
            const int sw   = (mrow & 7) << 4;
            sa[0][mt] = (f32x4){0.f, 0.f, 0.f, 0.f};
            sa[1][mt] = (f32x4){0.f, 0.f, 0.f, 0.f};
            #pragma unroll
            for (int kf = 0; kf < 4; ++kf) {
                bf16x8 kfrag = *(const bf16x8*)(Kc + (mrow << 8) + ((kf * 64 + lg * 16) ^ sw));
                sa[0][mt] = __builtin_amdgcn_mfma_f32_16x16x32_bf16(kfrag, qf[0][kf], sa[0][mt], 0, 0, 0);
                sa[1][mt] = __builtin_amdgcn_mfma_f32_16x16x32_bf16(kfrag, qf[1][kf], sa[1][mt], 0, 0, 0);
            }
        }
        __builtin_amdgcn_s_setprio(0);

        // per-strip row-max (q = lr; m spread over regs and lg)
        float tmv[2];
        #pragma unroll
        for (int s = 0; s < 2; ++s) {
            float tm = fmaxf(fmaxf(fmaxf(sa[s][0][0], sa[s][0][1]), fmaxf(sa[s][0][2], sa[s][0][3])),
                             fmaxf(fmaxf(sa[s][1][0], sa[s][1][1]), fmaxf(sa[s][1][2], sa[s][1][3])));
            tm = fmaxf(tm, fmaxf(fmaxf(fmaxf(sa[s][2][0], sa[s][2][1]), fmaxf(sa[s][2][2], sa[s][2][3])),
                                 fmaxf(fmaxf(sa[s][3][0], sa[s][3][1]), fmaxf(sa[s][3][2], sa[s][3][3]))));
            tm = fmaxf(tm, __shfl_xor(tm, 16));
            tm = fmaxf(tm, __shfl_xor(tm, 32));
            tmv[s] = tm;
        }

        // defer-max (T13): rescale only when max grows > 8 (log2 units)
        int need = (tmv[0] - m_run[0] > 8.f) || (tmv[1] - m_run[1] > 8.f);
        if (__any(need)) {
            #pragma unroll
            for (int s = 0; s < 2; ++s) {
                float mnew = fmaxf(m_run[s], tmv[s]);
                float sc   = __builtin_amdgcn_exp2f(m_run[s] - mnew);
                m_run[s] = mnew;
                l_run[s] *= sc;
                #pragma unroll
                for (int rr = 0; rr < 4; ++rr) {
                    float scb = __shfl(sc, (lane & 48) | (lg * 4 + rr));
                    #pragma unroll
                    for (int ct = 0; ct < 8; ++ct) yacc[s][ct][rr] *= scb;
                }
            }
        }

        // V-frags into regs early (shared by both strips; stays before fences)
        const char* Vc = V_sh[cur];
        bf16x8 vf[2][8];
        #pragma unroll
        for (int kf = 0; kf < 2; ++kf)
            #pragma unroll
            for (int ct = 0; ct < 8; ++ct) {
                const int vr = ct * 16 + lr;
                vf[kf][ct] = *(const bf16x8*)(Vc + (vr << 7) +
                                              ((kf * 64 + lg * 16) ^ ((vr & 7) << 4)));
            }

        // strip 0: exp2 + cvt_pk pack into per-wave P buf, then read pa0
        char* Pb = P_sh[w];
        bf16x8 pa0[2], pa1[2];
        {
            float rs = 0.f;
            #pragma unroll
            for (int mt = 0; mt < 4; ++mt) {
                float e0 = __builtin_amdgcn_exp2f(sa[0][mt][0] - m_run[0]);
                float e1 = __builtin_amdgcn_exp2f(sa[0][mt][1] - m_run[0]);
                float e2 = __builtin_amdgcn_exp2f(sa[0][mt][2] - m_run[0]);
                float e3 = __builtin_amdgcn_exp2f(sa[0][mt][3] - m_run[0]);
                rs += (e0 + e1) + (e2 + e3);
                u32x2 pk = {cvt_pk_bf16(e0, e1), cvt_pk_bf16(e2, e3)};
                *(u32x2*)(Pb + lr * 128 + ((mt * 32 + lg * 8) ^ ((lr & 7) << 4))) = pk;
            }
            rs += __shfl_xor(rs, 16);
            rs += __shfl_xor(rs, 32);
            l_run[0] += rs;
        }
        asm volatile("" ::: "memory");
        #pragma unroll
        for (int kf = 0; kf < 2; ++kf)
            pa0[kf] = *(const bf16x8*)(Pb + lr * 128 + ((kf * 64 + lg * 16) ^ ((lr & 7) << 4)));
        asm volatile("" ::: "memory");

        // strip 1: overwrite same P buf (same-wave DS is in-order; fenced)
        {
            float rs = 0.f;
            #pragma unroll
            for (int mt = 0; mt < 4; ++mt) {
                float e0 = __builtin_amdgcn_exp2f(sa[1][mt][0] - m_run[1]);
                float e1 = __builtin_amdgcn_exp2f(sa[1][mt][1] - m_run[1]);
                float e2 = __builtin_amdgcn_exp2f(sa[1][mt][2] - m_run[1]);
                float e3 = __builtin_amdgcn_exp2f(sa[1][mt][3] - m_run[1]);
                rs += (e0 + e1) + (e2 + e3);
                u32x2 pk = {cvt_pk_bf16(e0, e1), cvt_pk_bf16(e2, e3)};
                *(u32x2*)(Pb + lr * 128 + ((mt * 32 + lg * 8) ^ ((lr & 7) << 4))) = pk;
            }
            rs += __shfl_xor(rs, 16);
            rs += __shfl_xor(rs, 32);
            l_run[1] += rs;
        }
        asm volatile("" ::: "memory");
        #pragma unroll
        for (int kf = 0; kf < 2; ++kf)
            pa1[kf] = *(const bf16x8*)(Pb + lr * 128 + ((kf * 64 + lg * 16) ^ ((lr & 7) << 4)));

        // Y += P V  (all operands in registers)
        __builtin_amdgcn_s_setprio(1);
        #pragma unroll
        for (int kf = 0; kf < 2; ++kf)
            #pragma unroll
            for (int ct = 0; ct < 8; ++ct) {
                yacc[0][ct] = __builtin_amdgcn_mfma_f32_16x16x32_bf16(pa0[kf], vf[kf][ct], yacc[0][ct], 0, 0, 0);
                yacc[1][ct] = __builtin_amdgcn_mfma_f32_16x16x32_bf16(pa1[kf], vf[kf][ct], yacc[1][ct], 0, 0, 0);
            }
        __builtin_amdgcn_s_setprio(0);

        __syncthreads();   // drains vmcnt: next tile staged; buf[cur] reads done
    }

    // store UNNORMALIZED partial Yhat (fp32) + (m,l) per q-row
    float* yb = yh + ((size_t)half * BB + b) * NN * (size_t)CI;
    #pragma unroll
    for (int s = 0; s < 2; ++s) {
        #pragma unroll
        for (int rr = 0; rr < 4; ++rr) {
            int n = n0 + w * 32 + s * 16 + lg * 4 + rr;
            #pragma unroll
            for (int ct = 0; ct < 8; ++ct)
                yb[(size_t)n * CI + ct * 16 + lr] = yacc[s][ct][rr];
        }
    }
    if (lg == 0) {
        #pragma unroll
        for (int s = 0; s < 2; ++s) {
            int n = n0 + w * 32 + s * 16 + lr;
            f32x2 v = {m_run[s], l_run[s]};
            *(f32x2*)&ml[(((size_t)half * BB + b) * NN + n) * 2] = v;
        }
    }
}

// ---------------------------------------------------------------------------
// Kernel 2b: merge the two KV-half partials -> normalized Y^T bf16
// ---------------------------------------------------------------------------
__global__ __launch_bounds__(256) void merge_kernel(
    const float* __restrict__ yh, const float* __restrict__ ml,
    short* __restrict__ yp)
{
    const int tid = threadIdx.x;
    const int row = blockIdx.x * 8 + (tid >> 5);    // (b*NN + n) in [0, BB*NN)
    const int c4  = (tid & 31) * 4;
    const size_t H = (size_t)BB * NN * CI;          // half stride in yh
    const size_t R = (size_t)BB * NN * 2;           // half stride in ml

    float m0 = ml[(size_t)row * 2],     l0 = ml[(size_t)row * 2 + 1];
    float m1 = ml[R + (size_t)row * 2], l1 = ml[R + (size_t)row * 2 + 1];
    float mm = fmaxf(m0, m1);
    float w0 = __builtin_amdgcn_exp2f(m0 - mm);
    float w1 = __builtin_amdgcn_exp2f(m1 - mm);
    float inv = 1.0f / (l0 * w0 + l1 * w1);
    w0 *= inv; w1 *= inv;

    f32x4 a  = *(const f32x4*)&yh[(size_t)row * CI + c4];
    f32x4 bb = *(const f32x4*)&yh[H + (size_t)row * CI + c4];
    bf16x4 o;
    #pragma unroll
    for (int i = 0; i < 4; ++i) o[i] = f2bf(a[i] * w0 + bb[i] * w1);
    *(bf16x4*)&yp[(size_t)row * CI + c4] = o;
}

// ---------------------------------------------------------------------------
// Kernel 3: out = w_w @ Y + b_w + x.  M=o (coalesced n-stores), 128x128 tiles.
// ---------------------------------------------------------------------------
__global__ __launch_bounds__(256) void out_kernel(
    const short* __restrict__ yp, const float* __restrict__ ww,
    const float* __restrict__ bw, const float* __restrict__ x,
    float* __restrict__ out)
{
    __shared__ __align__(16) short A_lds[128][136];   // w_w [o][c]
    __shared__ __align__(16) short Bl[128][136];      // Y^T [n][c]

    const int tid = threadIdx.x;
    const int ob = blockIdx.x & 1;
    const int g  = blockIdx.x >> 1;
    const int b  = g >> 5;
    const int nn = (g & 31) * 128;
    const int o0 = ob * 128;
    const int w = tid >> 6, lane = tid & 63, lr = lane & 15, lg = lane >> 4;

    #pragma unroll
    for (int pass = 0; pass < 8; ++pass) {
        int o  = pass * 16 + (tid >> 4);
        int c8 = (tid & 15) * 8;
        f32x4 v0 = *(const f32x4*)&ww[(size_t)(o0 + o) * CI + c8];
        f32x4 v1 = *(const f32x4*)&ww[(size_t)(o0 + o) * CI + c8 + 4];
        bf16x8 bv;
        #pragma unroll
        for (int i = 0; i < 4; ++i) { bv[i] = f2bf(v0[i]); bv[4 + i] = f2bf(v1[i]); }
        *(bf16x8*)&A_lds[o][c8] = bv;
    }
    #pragma unroll
    for (int pass = 0; pass < 8; ++pass) {
        int n  = pass * 16 + (tid >> 4);
        int c8 = (tid & 15) * 8;
        *(bf16x8*)&Bl[n][c8] = *(const bf16x8*)&yp[((size_t)b * NN + nn + n) * CI + c8];
    }
    __syncthreads();

    f32x4 acc[2][8];
    #pragma unroll
    for (int i = 0; i < 2; ++i)
        #pragma unroll
        for (int j = 0; j < 8; ++j) acc[i][j] = (f32x4){0.f, 0.f, 0.f, 0.f};

    #pragma unroll
    for (int kf = 0; kf < 4; ++kf) {
        bf16x8 a0 = *(const bf16x8*)&A_lds[w * 32 + lr][kf * 32 + lg * 8];
        bf16x8 a1 = *(const bf16x8*)&A_lds[w * 32 + 16 + lr][kf * 32 + lg * 8];
        #pragma unroll
        for (int nt = 0; nt < 8; ++nt) {
            bf16x8 bv = *(const bf16x8*)&Bl[nt * 16 + lr][kf * 32 + lg * 8];
            acc[0][nt] = __builtin_amdgcn_mfma_f32_16x16x32_bf16(a0, bv, acc[0][nt], 0, 0, 0);
            acc[1][nt] = __builtin_amdgcn_mfma_f32_16x16x32_bf16(a1, bv, acc[1][nt], 0, 0, 0);
        }
    }

    #pragma unroll
    for (int wo = 0; wo < 2; ++wo) {
        #pragma unroll
        for (int rr = 0; rr < 4; ++rr) {
            int o = o0 + w * 32 + wo * 16 + lg * 4 + rr;
            float bias = bw[o];
            #pragma unroll
            for (int nt = 0; nt < 8; ++nt) {
                size_t idx = ((size_t)b * CIN + o) * NN + nn + nt * 16 + lr;
                out[idx] = acc[wo][nt][rr] + bias + x[idx];
            }
        }
    }
}

// ---------------------------------------------------------------------------
extern "C" void kernel_launch(void* const* d_in, const int* in_sizes, int n_in,
                              void* d_out, int out_size, void* d_ws, size_t ws_size,
                              hipStream_t stream)
{
    const float* x     = (const float*)d_in[0];
    const float* gamma = (const float*)d_in[1];
    const float* beta  = (const float*)d_in[2];
    const float* mean  = (const float*)d_in[3];
    const float* var   = (const float*)d_in[4];
    const float* wg    = (const float*)d_in[5];
    const float* bg    = (const float*)d_in[6];
    const float* wth   = (const float*)d_in[7];
    const float* bth   = (const float*)d_in[8];
    const float* wph   = (const float*)d_in[9];
    const float* bph   = (const float*)d_in[10];
    const float* ww    = (const float*)d_in[11];
    const float* bw    = (const float*)d_in[12];

    // ws layout: qp 8MB | kp 8MB | vtp 8MB | ml 0.5MB  (yp aliases qp after attn)
    // d_out (32MB fp32) doubles as Yhat partial scratch between attn and out.
    const size_t seg = (size_t)BB * NN * CI;
    short* qp  = (short*)d_ws;
    short* kp  = qp + seg;
    short* vtp = kp + seg;
    float* ml  = (float*)(vtp + seg);
    short* yp  = qp;                       // reuse: q dead after attn
    float* yh  = (float*)d_out;            // [2][B][N][CI] partials
    (void)in_sizes; (void)n_in; (void)out_size; (void)ws_size;

    proj_kernel<<<3 * BB * (NN / 64), 256, 0, stream>>>(
        x, gamma, beta, mean, var, wg, bg, wth, bth, wph, bph, qp, kp, vtp);
    attn_kernel<<<2 * BB * (NN / 128), 256, 0, stream>>>(qp, kp, vtp, yh, ml);
    merge_kernel<<<BB * NN / 8, 256, 0, stream>>>(yh, ml, yp);
    out_kernel<<<2 * BB * (NN / 128), 256, 0, stream>>>(yp, ww, bw, x, (float*)d_out);
}

// Round 5
// 133.746 us; speedup vs baseline: 1.3986x; 1.1382x over previous
//
#include <hip/hip_runtime.h>
#include <hip/hip_bf16.h>
#include <stdint.h>

#define BB   8
#define CIN  256
#define CI   128
#define NN   4096
#define EPSV 1e-5f
#define LOG2E 1.44269504088896340736f

typedef __attribute__((ext_vector_type(8))) short bf16x8;
typedef __attribute__((ext_vector_type(4))) short bf16x4;
typedef __attribute__((ext_vector_type(4))) float f32x4;
typedef __attribute__((ext_vector_type(2))) float f32x2;
typedef __attribute__((ext_vector_type(2))) unsigned int u32x2;

static __device__ inline short f2bf(float f) {
    uint32_t u = __builtin_bit_cast(uint32_t, f);
    u += 0x7FFFu + ((u >> 16) & 1u);   // round-to-nearest-even
    return (short)(u >> 16);
}

static __device__ inline float bf2f(short s) {
    uint32_t u = ((uint32_t)(uint16_t)s) << 16;
    return __builtin_bit_cast(float, u);
}

static __device__ inline uint32_t cvt_pk_bf16(float lo, float hi) {
    uint32_t r;
    asm("v_cvt_pk_bf16_f32 %0, %1, %2" : "=v"(r) : "v"(lo), "v"(hi));
    return r;
}

// ---------------------------------------------------------------------------
// Kernel 1 (FUSED): BN + all three 1x1 projections in one pass over x.
// BN(x) tile staged ONCE as bf16 [64n][256c]; loop s in {theta,phi,g} with a
// single reusable B-chunk buffer; only acc[8] live per s (low VGPR).
// grid: B * (N/64) = 512, batch = bid&7 (XCD-pinned x reads).
// ---------------------------------------------------------------------------
__global__ __launch_bounds__(256, 2) void proj_kernel(
    const float* __restrict__ x,
    const float* __restrict__ gamma, const float* __restrict__ beta,
    const float* __restrict__ mean,  const float* __restrict__ var,
    const float* __restrict__ wg,  const float* __restrict__ bg,
    const float* __restrict__ wth, const float* __restrict__ bth,
    const float* __restrict__ wph, const float* __restrict__ bph,
    short* __restrict__ qp, short* __restrict__ kp, short* __restrict__ vtp)
{
    __shared__ float s_scale[CIN];
    __shared__ float s_shift[CIN];
    __shared__ __align__(16) short A_lds[64][264];   // [n][c] full K, pad 264
    __shared__ __align__(16) short B_lds[128][72];   // [o][c-chunk], reused x12

    const int tid = threadIdx.x;
    const int b   = blockIdx.x & 7;           // batch == XCD
    const int n0  = (blockIdx.x >> 3) * 64;
    const int w = tid >> 6, lane = tid & 63, lr = lane & 15, lg = lane >> 4;

    {   // BN scale/shift (256 threads == 256 channels)
        float sc = gamma[tid] * rsqrtf(var[tid] + EPSV);
        s_scale[tid] = sc;
        s_shift[tid] = beta[tid] - mean[tid] * sc;
    }
    __syncthreads();

    // stage BN(x) -> A_lds[n][c] bf16, once (16 passes)
    #pragma unroll
    for (int p = 0; p < 16; ++p) {
        int c  = p * 16 + (tid >> 4);
        int n4 = (tid & 15) * 4;
        f32x4 v = *(const f32x4*)&x[((size_t)b * CIN + c) * NN + n0 + n4];
        float sc = s_scale[c], sh = s_shift[c];
        #pragma unroll
        for (int i = 0; i < 4; ++i)
            A_lds[n4 + i][c] = f2bf(v[i] * sc + sh);
    }
    __syncthreads();

    const float* WS[3] = {wth, wph, wg};
    const float* BS[3] = {bth, bph, bg};

    #pragma unroll
    for (int s = 0; s < 3; ++s) {
        f32x4 acc[8];
        #pragma unroll
        for (int i = 0; i < 8; ++i) acc[i] = (f32x4){0.f, 0.f, 0.f, 0.f};

        for (int c0 = 0; c0 < CIN; c0 += 64) {
            // stage B chunk [o][c0..c0+63]
            #pragma unroll
            for (int p = 0; p < 8; ++p) {
                int o  = p * 16 + (tid >> 4);
                int c4 = (tid & 15) * 4;
                f32x4 v = *(const f32x4*)&WS[s][(size_t)o * CIN + c0 + c4];
                bf16x4 bv;
                #pragma unroll
                for (int i = 0; i < 4; ++i) bv[i] = f2bf(v[i]);
                *(bf16x4*)&B_lds[o][c4] = bv;
            }
            __syncthreads();

            bf16x8 a0 = *(const bf16x8*)&A_lds[w * 16 + lr][c0 + lg * 8];
            bf16x8 a1 = *(const bf16x8*)&A_lds[w * 16 + lr][c0 + 32 + lg * 8];
            #pragma unroll
            for (int ot = 0; ot < 8; ++ot) {
                bf16x8 b0 = *(const bf16x8*)&B_lds[ot * 16 + lr][lg * 8];
                bf16x8 b1 = *(const bf16x8*)&B_lds[ot * 16 + lr][32 + lg * 8];
                acc[ot] = __builtin_amdgcn_mfma_f32_16x16x32_bf16(a0, b0, acc[ot], 0, 0, 0);
                acc[ot] = __builtin_amdgcn_mfma_f32_16x16x32_bf16(a1, b1, acc[ot], 0, 0, 0);
            }
            __syncthreads();
        }

        if (s < 2) {   // Q / K: (b, n, c) row-major; Q scaled by log2e
            short* dst = (s == 0) ? qp : kp;
            const float om = (s == 0) ? LOG2E : 1.0f;
            #pragma unroll
            for (int ot = 0; ot < 8; ++ot) {
                float bias = BS[s][ot * 16 + lr];
                #pragma unroll
                for (int rr = 0; rr < 4; ++rr) {
                    int n = n0 + w * 16 + lg * 4 + rr;
                    dst[((size_t)b * NN + n) * CI + ot * 16 + lr] = f2bf((acc[ot][rr] + bias) * om);
                }
            }
        } else {       // V^T: (b, c, n)
            #pragma unroll
            for (int ot = 0; ot < 8; ++ot) {
                float bias = BS[s][ot * 16 + lr];
                bf16x4 pk;
                #pragma unroll
                for (int rr = 0; rr < 4; ++rr) pk[rr] = f2bf(acc[ot][rr] + bias);
                *(bf16x4*)&vtp[((size_t)b * CI + ot * 16 + lr) * NN + n0 + w * 16 + lg * 4] = pk;
            }
        }
    }
}

// ---------------------------------------------------------------------------
// Kernel 2: flash attention, SPLIT-KV. grid 512 = 8 batch x 2 kv-half x 32
// q-tiles -> 2 blocks/CU. 4 waves x 2 Q-strips. Loop-carried stage pointers.
// Writes UNNORMALIZED bf16 partial Yhat (into d_out scratch) + (m,l) to ml.
// ---------------------------------------------------------------------------
__global__ __launch_bounds__(256, 2) void attn_kernel(
    const short* __restrict__ qp, const short* __restrict__ kp,
    const short* __restrict__ vtp, short* __restrict__ yh,
    float* __restrict__ ml)
{
    __shared__ __align__(16) char K_sh[2][64 * 256];    // [m][c] swizzled, 16KB x2
    __shared__ __align__(16) char V_sh[2][128 * 128];   // [c][m] swizzled, 16KB x2
    __shared__ __align__(16) char P_sh[4][16 * 128];    // per-wave single P buf

    const int tid  = threadIdx.x;
    const int b    = blockIdx.x & 7;            // batch == XCD (round-robin)
    const int half = (blockIdx.x >> 3) & 1;     // kv half
    const int n0   = (blockIdx.x >> 4) * 128;
    const int w = tid >> 6, lane = tid & 63, lr = lane & 15, lg = lane >> 4;
    const int NT = NN / 128;                    // 32 kv tiles per half
    const int t0 = half * NT;

    // loop-carried per-lane global source pointers (pre-swizzled), LDS dest linear
    const char* kgp[4];
    const char* vgp[4];
    #pragma unroll
    for (int r = 0; r < 4; ++r) {
        int idx = ((r * 4 + w) << 6) + lane;          // 16B-chunk index 0..1023
        int mm  = idx >> 4, cb = (idx & 15) << 4;     // K: row m, dest col-byte
        kgp[r] = (const char*)(kp + (size_t)b * NN * CI + (size_t)t0 * 64 * CI
                               + (size_t)mm * CI) + (cb ^ ((mm & 7) << 4));
        int cc = idx >> 3, cbv = (idx & 7) << 4;      // V: row c, dest col-byte
        vgp[r] = (const char*)(vtp + (size_t)b * CI * NN + (size_t)t0 * 64
                               + (size_t)cc * NN) + (cbv ^ ((cc & 7) << 4));
    }
    auto stage = [&](int bufi) {
        #pragma unroll
        for (int r = 0; r < 4; ++r) {
            __builtin_amdgcn_global_load_lds(
                (const __attribute__((address_space(1))) void*)kgp[r],
                (__attribute__((address_space(3))) void*)&K_sh[bufi][(r * 4 + w) << 10],
                16, 0, 0);
            __builtin_amdgcn_global_load_lds(
                (const __attribute__((address_space(1))) void*)vgp[r],
                (__attribute__((address_space(3))) void*)&V_sh[bufi][(r * 4 + w) << 10],
                16, 0, 0);
            kgp[r] += 64 * CI * 2;    // next K tile: 16 KB
            vgp[r] += 64 * 2;         // next V tile: 128 B
        }
    };

    // Q strips in registers (B-frag for mfma(K,Q): col=q=lr, k contiguous)
    bf16x8 qf[2][4];
    #pragma unroll
    for (int s = 0; s < 2; ++s) {
        const short* qrow = qp + ((size_t)b * NN + n0 + w * 32 + s * 16 + lr) * CI;
        #pragma unroll
        for (int kf = 0; kf < 4; ++kf)
            qf[s][kf] = *(const bf16x8*)&qrow[kf * 32 + lg * 8];
    }

    f32x4 yacc[2][8];
    #pragma unroll
    for (int s = 0; s < 2; ++s)
        #pragma unroll
        for (int i = 0; i < 8; ++i) yacc[s][i] = (f32x4){0.f, 0.f, 0.f, 0.f};
    float m_run[2] = {-__builtin_huge_valf(), -__builtin_huge_valf()};
    float l_run[2] = {0.f, 0.f};

    stage(0);
    __syncthreads();

    for (int t = 0; t < NT; ++t) {
        const int cur = t & 1;
        if (t + 1 < NT) stage(cur ^ 1);   // issue before compute

        // S^T = K Q : lane (lr,lg) holds S[q=lr][m=mt*16+lg*4+rr] per strip
        const char* Kc = K_sh[cur];
        f32x4 sa[2][4];
        __builtin_amdgcn_s_setprio(1);
        #pragma unroll
        for (int mt = 0; mt < 4; ++mt) {
            const int mrow = mt * 16 + lr;
            const int sw   = (mrow & 7) << 4;
            sa[0][mt] = (f32x4){0.f, 0.f, 0.f, 0.f};
            sa[1][mt] = (f32x4){0.f, 0.f, 0.f, 0.f};
            #pragma unroll
            for (int kf = 0; kf < 4; ++kf) {
                bf16x8 kfrag = *(const bf16x8*)(Kc + (mrow << 8) + ((kf * 64 + lg * 16) ^ sw));
                sa[0][mt] = __builtin_amdgcn_mfma_f32_16x16x32_bf16(kfrag, qf[0][kf], sa[0][mt], 0, 0, 0);
                sa[1][mt] = __builtin_amdgcn_mfma_f32_16x16x32_bf16(kfrag, qf[1][kf], sa[1][mt], 0, 0, 0);
            }
        }
        __builtin_amdgcn_s_setprio(0);

        // per-strip row-max (q = lr; m spread over regs and lg)
        float tmv[2];
        #pragma unroll
        for (int s = 0; s < 2; ++s) {
            float tm = fmaxf(fmaxf(fmaxf(sa[s][0][0], sa[s][0][1]), fmaxf(sa[s][0][2], sa[s][0][3])),
                             fmaxf(fmaxf(sa[s][1][0], sa[s][1][1]), fmaxf(sa[s][1][2], sa[s][1][3])));
            tm = fmaxf(tm, fmaxf(fmaxf(fmaxf(sa[s][2][0], sa[s][2][1]), fmaxf(sa[s][2][2], sa[s][2][3])),
                                 fmaxf(fmaxf(sa[s][3][0], sa[s][3][1]), fmaxf(sa[s][3][2], sa[s][3][3]))));
            tm = fmaxf(tm, __shfl_xor(tm, 16));
            tm = fmaxf(tm, __shfl_xor(tm, 32));
            tmv[s] = tm;
        }

        // defer-max (T13): rescale only when max grows > 8 (log2 units)
        int need = (tmv[0] - m_run[0] > 8.f) || (tmv[1] - m_run[1] > 8.f);
        if (__any(need)) {
            #pragma unroll
            for (int s = 0; s < 2; ++s) {
                float mnew = fmaxf(m_run[s], tmv[s]);
                float sc   = __builtin_amdgcn_exp2f(m_run[s] - mnew);
                m_run[s] = mnew;
                l_run[s] *= sc;
                #pragma unroll
                for (int rr = 0; rr < 4; ++rr) {
                    float scb = __shfl(sc, (lane & 48) | (lg * 4 + rr));
                    #pragma unroll
                    for (int ct = 0; ct < 8; ++ct) yacc[s][ct][rr] *= scb;
                }
            }
        }

        // V-frags into regs early (shared by both strips)
        const char* Vc = V_sh[cur];
        bf16x8 vf[2][8];
        #pragma unroll
        for (int kf = 0; kf < 2; ++kf)
            #pragma unroll
            for (int ct = 0; ct < 8; ++ct) {
                const int vr = ct * 16 + lr;
                vf[kf][ct] = *(const bf16x8*)(Vc + (vr << 7) +
                                              ((kf * 64 + lg * 16) ^ ((vr & 7) << 4)));
            }

        // strip 0: exp2 + cvt_pk pack into per-wave P buf, then read pa0
        char* Pb = P_sh[w];
        bf16x8 pa0[2], pa1[2];
        {
            float rs = 0.f;
            #pragma unroll
            for (int mt = 0; mt < 4; ++mt) {
                float e0 = __builtin_amdgcn_exp2f(sa[0][mt][0] - m_run[0]);
                float e1 = __builtin_amdgcn_exp2f(sa[0][mt][1] - m_run[0]);
                float e2 = __builtin_amdgcn_exp2f(sa[0][mt][2] - m_run[0]);
                float e3 = __builtin_amdgcn_exp2f(sa[0][mt][3] - m_run[0]);
                rs += (e0 + e1) + (e2 + e3);
                u32x2 pk = {cvt_pk_bf16(e0, e1), cvt_pk_bf16(e2, e3)};
                *(u32x2*)(Pb + lr * 128 + ((mt * 32 + lg * 8) ^ ((lr & 7) << 4))) = pk;
            }
            rs += __shfl_xor(rs, 16);
            rs += __shfl_xor(rs, 32);
            l_run[0] += rs;
        }
        asm volatile("" ::: "memory");
        #pragma unroll
        for (int kf = 0; kf < 2; ++kf)
            pa0[kf] = *(const bf16x8*)(Pb + lr * 128 + ((kf * 64 + lg * 16) ^ ((lr & 7) << 4)));
        asm volatile("" ::: "memory");

        // strip 1: overwrite same P buf (same-wave DS is in-order; fenced)
        {
            float rs = 0.f;
            #pragma unroll
            for (int mt = 0; mt < 4; ++mt) {
                float e0 = __builtin_amdgcn_exp2f(sa[1][mt][0] - m_run[1]);
                float e1 = __builtin_amdgcn_exp2f(sa[1][mt][1] - m_run[1]);
                float e2 = __builtin_amdgcn_exp2f(sa[1][mt][2] - m_run[1]);
                float e3 = __builtin_amdgcn_exp2f(sa[1][mt][3] - m_run[1]);
                rs += (e0 + e1) + (e2 + e3);
                u32x2 pk = {cvt_pk_bf16(e0, e1), cvt_pk_bf16(e2, e3)};
                *(u32x2*)(Pb + lr * 128 + ((mt * 32 + lg * 8) ^ ((lr & 7) << 4))) = pk;
            }
            rs += __shfl_xor(rs, 16);
            rs += __shfl_xor(rs, 32);
            l_run[1] += rs;
        }
        asm volatile("" ::: "memory");
        #pragma unroll
        for (int kf = 0; kf < 2; ++kf)
            pa1[kf] = *(const bf16x8*)(Pb + lr * 128 + ((kf * 64 + lg * 16) ^ ((lr & 7) << 4)));

        // Y += P V  (all operands in registers)
        __builtin_amdgcn_s_setprio(1);
        #pragma unroll
        for (int kf = 0; kf < 2; ++kf)
            #pragma unroll
            for (int ct = 0; ct < 8; ++ct) {
                yacc[0][ct] = __builtin_amdgcn_mfma_f32_16x16x32_bf16(pa0[kf], vf[kf][ct], yacc[0][ct], 0, 0, 0);
                yacc[1][ct] = __builtin_amdgcn_mfma_f32_16x16x32_bf16(pa1[kf], vf[kf][ct], yacc[1][ct], 0, 0, 0);
            }
        __builtin_amdgcn_s_setprio(0);

        __syncthreads();   // drains vmcnt: next tile staged; buf[cur] reads done
    }

    // store UNNORMALIZED partial Yhat (bf16) + (m,l) per q-row
    short* yb = yh + ((size_t)half * BB + b) * NN * (size_t)CI;
    #pragma unroll
    for (int s = 0; s < 2; ++s) {
        #pragma unroll
        for (int rr = 0; rr < 4; ++rr) {
            int n = n0 + w * 32 + s * 16 + lg * 4 + rr;
            #pragma unroll
            for (int ct = 0; ct < 8; ++ct)
                yb[(size_t)n * CI + ct * 16 + lr] = f2bf(yacc[s][ct][rr]);
        }
    }
    if (lg == 0) {
        #pragma unroll
        for (int s = 0; s < 2; ++s) {
            int n = n0 + w * 32 + s * 16 + lr;
            f32x2 v = {m_run[s], l_run[s]};
            *(f32x2*)&ml[(((size_t)half * BB + b) * NN + n) * 2] = v;
        }
    }
}

// ---------------------------------------------------------------------------
// Kernel 2b: merge the two KV-half bf16 partials -> normalized Y^T bf16
// ---------------------------------------------------------------------------
__global__ __launch_bounds__(256) void merge_kernel(
    const short* __restrict__ yh, const float* __restrict__ ml,
    short* __restrict__ yp)
{
    const int tid = threadIdx.x;
    const int row = blockIdx.x * 8 + (tid >> 5);    // (b*NN + n) in [0, BB*NN)
    const int c4  = (tid & 31) * 4;
    const size_t H = (size_t)BB * NN * CI;          // half stride in yh
    const size_t R = (size_t)BB * NN * 2;           // half stride in ml

    float m0 = ml[(size_t)row * 2],     l0 = ml[(size_t)row * 2 + 1];
    float m1 = ml[R + (size_t)row * 2], l1 = ml[R + (size_t)row * 2 + 1];
    float mm = fmaxf(m0, m1);
    float w0 = __builtin_amdgcn_exp2f(m0 - mm);
    float w1 = __builtin_amdgcn_exp2f(m1 - mm);
    float inv = 1.0f / (l0 * w0 + l1 * w1);
    w0 *= inv; w1 *= inv;

    bf16x4 a  = *(const bf16x4*)&yh[(size_t)row * CI + c4];
    bf16x4 bb = *(const bf16x4*)&yh[H + (size_t)row * CI + c4];
    bf16x4 o;
    #pragma unroll
    for (int i = 0; i < 4; ++i) o[i] = f2bf(bf2f(a[i]) * w0 + bf2f(bb[i]) * w1);
    *(bf16x4*)&yp[(size_t)row * CI + c4] = o;
}

// ---------------------------------------------------------------------------
// Kernel 3: out = w_w @ Y + b_w + x.  M=o (coalesced n-stores), 128x128 tiles.
// ---------------------------------------------------------------------------
__global__ __launch_bounds__(256) void out_kernel(
    const short* __restrict__ yp, const float* __restrict__ ww,
    const float* __restrict__ bw, const float* __restrict__ x,
    float* __restrict__ out)
{
    __shared__ __align__(16) short A_lds[128][136];   // w_w [o][c]
    __shared__ __align__(16) short Bl[128][136];      // Y^T [n][c]

    const int tid = threadIdx.x;
    const int ob = blockIdx.x & 1;
    const int g  = blockIdx.x >> 1;
    const int b  = g >> 5;
    const int nn = (g & 31) * 128;
    const int o0 = ob * 128;
    const int w = tid >> 6, lane = tid & 63, lr = lane & 15, lg = lane >> 4;

    #pragma unroll
    for (int pass = 0; pass < 8; ++pass) {
        int o  = pass * 16 + (tid >> 4);
        int c8 = (tid & 15) * 8;
        f32x4 v0 = *(const f32x4*)&ww[(size_t)(o0 + o) * CI + c8];
        f32x4 v1 = *(const f32x4*)&ww[(size_t)(o0 + o) * CI + c8 + 4];
        bf16x8 bv;
        #pragma unroll
        for (int i = 0; i < 4; ++i) { bv[i] = f2bf(v0[i]); bv[4 + i] = f2bf(v1[i]); }
        *(bf16x8*)&A_lds[o][c8] = bv;
    }
    #pragma unroll
    for (int pass = 0; pass < 8; ++pass) {
        int n  = pass * 16 + (tid >> 4);
        int c8 = (tid & 15) * 8;
        *(bf16x8*)&Bl[n][c8] = *(const bf16x8*)&yp[((size_t)b * NN + nn + n) * CI + c8];
    }
    __syncthreads();

    f32x4 acc[2][8];
    #pragma unroll
    for (int i = 0; i < 2; ++i)
        #pragma unroll
        for (int j = 0; j < 8; ++j) acc[i][j] = (f32x4){0.f, 0.f, 0.f, 0.f};

    #pragma unroll
    for (int kf = 0; kf < 4; ++kf) {
        bf16x8 a0 = *(const bf16x8*)&A_lds[w * 32 + lr][kf * 32 + lg * 8];
        bf16x8 a1 = *(const bf16x8*)&A_lds[w * 32 + 16 + lr][kf * 32 + lg * 8];
        #pragma unroll
        for (int nt = 0; nt < 8; ++nt) {
            bf16x8 bv = *(const bf16x8*)&Bl[nt * 16 + lr][kf * 32 + lg * 8];
            acc[0][nt] = __builtin_amdgcn_mfma_f32_16x16x32_bf16(a0, bv, acc[0][nt], 0, 0, 0);
            acc[1][nt] = __builtin_amdgcn_mfma_f32_16x16x32_bf16(a1, bv, acc[1][nt], 0, 0, 0);
        }
    }

    #pragma unroll
    for (int wo = 0; wo < 2; ++wo) {
        #pragma unroll
        for (int rr = 0; rr < 4; ++rr) {
            int o = o0 + w * 32 + wo * 16 + lg * 4 + rr;
            float bias = bw[o];
            #pragma unroll
            for (int nt = 0; nt < 8; ++nt) {
                size_t idx = ((size_t)b * CIN + o) * NN + nn + nt * 16 + lr;
                out[idx] = acc[wo][nt][rr] + bias + x[idx];
            }
        }
    }
}

// ---------------------------------------------------------------------------
extern "C" void kernel_launch(void* const* d_in, const int* in_sizes, int n_in,
                              void* d_out, int out_size, void* d_ws, size_t ws_size,
                              hipStream_t stream)
{
    const float* x     = (const float*)d_in[0];
    const float* gamma = (const float*)d_in[1];
    const float* beta  = (const float*)d_in[2];
    const float* mean  = (const float*)d_in[3];
    const float* var   = (const float*)d_in[4];
    const float* wg    = (const float*)d_in[5];
    const float* bg    = (const float*)d_in[6];
    const float* wth   = (const float*)d_in[7];
    const float* bth   = (const float*)d_in[8];
    const float* wph   = (const float*)d_in[9];
    const float* bph   = (const float*)d_in[10];
    const float* ww    = (const float*)d_in[11];
    const float* bw    = (const float*)d_in[12];

    // ws layout: qp 8MB | kp 8MB | vtp 8MB | ml 0.5MB  (yp aliases qp after attn)
    // d_out (32MB) doubles as bf16 Yhat partial scratch (2 x 8MB) between
    // attn and merge; out_kernel then overwrites d_out fully.
    const size_t seg = (size_t)BB * NN * CI;
    short* qp  = (short*)d_ws;
    short* kp  = qp + seg;
    short* vtp = kp + seg;
    float* ml  = (float*)(vtp + seg);
    short* yp  = qp;                       // reuse: q dead after attn
    short* yh  = (short*)d_out;            // [2][B][N][CI] bf16 partials
    (void)in_sizes; (void)n_in; (void)out_size; (void)ws_size;

    proj_kernel<<<BB * (NN / 64), 256, 0, stream>>>(
        x, gamma, beta, mean, var, wg, bg, wth, bth, wph, bph, qp, kp, vtp);
    attn_kernel<<<2 * BB * (NN / 128), 256, 0, stream>>>(qp, kp, vtp, yh, ml);
    merge_kernel<<<BB * NN / 8, 256, 0, stream>>>(yh, ml, yp);
    out_kernel<<<2 * BB * (NN / 128), 256, 0, stream>>>(yp, ww, bw, x, (float*)d_out);
}